// Round 6
// baseline (143.166 us; speedup 1.0000x reference)
//
#include <hip/hip_runtime.h>

typedef float  f32x4 __attribute__((ext_vector_type(4)));
typedef short  s16x8 __attribute__((ext_vector_type(8)));

__device__ __forceinline__ unsigned short f2bf(float f){
    unsigned int u = __float_as_uint(f);
    u = u + 0x7FFFu + ((u >> 16) & 1u);      // RNE
    return (unsigned short)(u >> 16);
}

// ---------------- K0a: transpose+cast W[256][256] f32 -> WT bf16 [c][k] ----------------
__global__ void k_wt(const float* __restrict__ W, unsigned short* __restrict__ WT){
    int c = blockIdx.x, k = threadIdx.x;
    WT[c*256 + k] = f2bf(W[k*256 + c]);
}

// ---------------- K0b: mask -> bitmask (1 bit per entry), row-major u64 chunks ----------
__global__ void k_bits(const int* __restrict__ mask, unsigned long long* __restrict__ bits64){
    int i = blockIdx.x;
    int wave = threadIdx.x >> 6, lane = threadIdx.x & 63;
    for (int c = wave; c < 32; c += 4){
        int v = mask[i*2048 + c*64 + lane];
        unsigned long long b = __ballot(v != 0);
        if (lane == 0) bits64[i*32 + c] = b;
    }
}

// ---------------- K1: h = x @ W, all heads per block (R2-validated 16-acc structure),
// fused src/dst (R5-validated reduction), hTt store (R5-validated re-index).
// grid 128, block 256 = 4 waves, wave = 16 rows x 256 cols.
__global__ __launch_bounds__(256) void k_gemm(const float* __restrict__ x,
        const unsigned short* __restrict__ WT,
        const float* __restrict__ a_src, const float* __restrict__ a_dst,
        unsigned short* __restrict__ hTt, float* __restrict__ src, float* __restrict__ dst){
    const int wave = threadIdx.x >> 6, lane = threadIdx.x & 63;
    const int q = lane >> 4, t = lane & 15;
    const int m0 = blockIdx.x*64 + wave*16;   // row tile (r = b*2048+n)
    f32x4 acc[16];
#pragma unroll
    for (int i = 0; i < 16; i++) acc[i] = (f32x4){0.f,0.f,0.f,0.f};
    const int row = m0 + t;
    for (int k = 0; k < 256; k += 32){
        int kk = k + q*8;
        const float* xp = x + row*256 + kk;
        f32x4 x0 = *reinterpret_cast<const f32x4*>(xp);
        f32x4 x1 = *reinterpret_cast<const f32x4*>(xp + 4);
        s16x8 a;
#pragma unroll
        for (int j = 0; j < 4; j++){ a[j] = (short)f2bf(x0[j]); a[j+4] = (short)f2bf(x1[j]); }
#pragma unroll
        for (int dblk = 0; dblk < 16; dblk++){
            s16x8 bfr = *reinterpret_cast<const s16x8*>(WT + (dblk*16 + t)*256 + kk);
            acc[dblk] = __builtin_amdgcn_mfma_f32_16x16x32_bf16(a, bfr, acc[dblk], 0, 0, 0);
        }
    }
    const int b = m0 >> 11;                   // tile never straddles batch boundary
    const int jb = (m0 & 2047) >> 4;
    // fused src/dst: acc[dblk][reg] = h[row=m0+q*4+reg][col dg=dblk*16+t]
    float as_[16], ad_[16];
#pragma unroll
    for (int dblk = 0; dblk < 16; dblk++){
        as_[dblk] = a_src[dblk*16 + t];       // dg = head*64 + dlocal = dblk*16 + t
        ad_[dblk] = a_dst[dblk*16 + t];
    }
#pragma unroll
    for (int reg = 0; reg < 4; reg++){
        float sv[4] = {0,0,0,0}, dv[4] = {0,0,0,0};
#pragma unroll
        for (int dblk = 0; dblk < 16; dblk++){
            int hh = dblk >> 2;
            sv[hh] += acc[dblk][reg]*as_[dblk];
            dv[hh] += acc[dblk][reg]*ad_[dblk];
        }
#pragma unroll
        for (int off = 1; off < 16; off <<= 1){
#pragma unroll
            for (int hh = 0; hh < 4; hh++){
                sv[hh] += __shfl_xor(sv[hh], off);
                dv[hh] += __shfl_xor(dv[hh], off);
            }
        }
        if (t == 0){
            int n = (m0 & 2047) + q*4 + reg;
#pragma unroll
            for (int hh = 0; hh < 4; hh++){
                src[(b*4 + hh)*2048 + n] = sv[hh];
                dst[(b*4 + hh)*2048 + n] = dv[hh];
            }
        }
    }
    // hTt store [bh][jb][d][jj] (R5-validated formula; head = dblk>>2, dlocal = (dblk&3)*16+t)
#pragma unroll
    for (int dblk = 0; dblk < 16; dblk++){
        int bh = b*4 + (dblk >> 2);
        int d  = (dblk & 3)*16 + t;
#pragma unroll
        for (int reg = 0; reg < 4; reg++){
            int jj = q*4 + reg;               // n = m0 + jj
            hTt[((bh*128 + jb)*64 + d)*16 + jj] = f2bf(acc[dblk][reg]);
        }
    }
}

// ---------------- K2: fused masked softmax + PV + ELU (R5 structure + ones-MFMA S) ------
// grid (16 bh, 128 i-tiles of 16 rows), block 256 = 4 waves, wave = 512-wide j-chunk.
__global__ __launch_bounds__(256, 4) void k_attn(const unsigned short* __restrict__ hTt,
        const unsigned int* __restrict__ bits, const float* __restrict__ src,
        const float* __restrict__ dst, float* __restrict__ out){
    __shared__ float accL[4][16][64];
    __shared__ float Sl[4][16];
    const int bh = blockIdx.x;
    const int b = bh >> 2, head = bh & 3;
    const int wave = threadIdx.x >> 6, lane = threadIdx.x & 63;
    const int q = lane >> 4, t = lane & 15, q8 = q*8;
    const int i0 = blockIdx.y*16;
    const int i = i0 + t;                                  // A row of this lane
    const float NEGINF = -__builtin_inff();
    const float vsrc = src[bh*2048 + i];
    const unsigned int* bR = bits + i*64 + wave*16;        // u32 word covers 32 j-cols
    const float* dR = dst + bh*2048 + wave*512 + q8;
    const unsigned short* vB = hTt + bh*131072 + wave*32768 + (q>>1)*1024 + (q&1)*8 + t*16;
    f32x4 acc0 = {0,0,0,0}, acc1 = {0,0,0,0}, acc2 = {0,0,0,0}, acc3 = {0,0,0,0};
    f32x4 sacc = {0,0,0,0};
    s16x8 ones;
#pragma unroll
    for (int j = 0; j < 8; j++) ones[j] = (short)0x3F80;   // bf16 1.0
    for (int it = 0; it < 16; ++it){
        const unsigned short* vp = vB + it*2048;
        s16x8 h0 = *reinterpret_cast<const s16x8*>(vp);
        s16x8 h1 = *reinterpret_cast<const s16x8*>(vp + 256);
        s16x8 h2 = *reinterpret_cast<const s16x8*>(vp + 512);
        s16x8 h3 = *reinterpret_cast<const s16x8*>(vp + 768);
        unsigned int bs = bR[it] >> q8;
        f32x4 d0 = *reinterpret_cast<const f32x4*>(dR + it*32);
        f32x4 d1 = *reinterpret_cast<const f32x4*>(dR + it*32 + 4);
        float e[8];
#pragma unroll
        for (int jj = 0; jj < 8; jj++){
            float dvv = (jj < 4) ? d0[jj] : d1[jj-4];
            float lg = vsrc + dvv;
            lg = fmaxf(lg, 0.2f*lg);                       // leaky relu
            lg = ((bs >> jj) & 1u) ? lg : NEGINF;          // mask -> exp = 0
            e[jj] = __expf(lg);                            // bounded logits: no max-sub
        }
        union { unsigned int u[4]; s16x8 s; } pk;
#pragma unroll
        for (int p = 0; p < 4; p++)
            pk.u[p] = __builtin_amdgcn_perm(__float_as_uint(e[2*p+1]), __float_as_uint(e[2*p]), 0x07060302u);
        acc0 = __builtin_amdgcn_mfma_f32_16x16x32_bf16(pk.s, h0, acc0, 0,0,0);
        acc1 = __builtin_amdgcn_mfma_f32_16x16x32_bf16(pk.s, h1, acc1, 0,0,0);
        acc2 = __builtin_amdgcn_mfma_f32_16x16x32_bf16(pk.s, h2, acc2, 0,0,0);
        acc3 = __builtin_amdgcn_mfma_f32_16x16x32_bf16(pk.s, h3, acc3, 0,0,0);
        sacc = __builtin_amdgcn_mfma_f32_16x16x32_bf16(pk.s, ones, sacc, 0,0,0);
    }
#pragma unroll
    for (int reg = 0; reg < 4; reg++){
        int r = q*4 + reg;
        accL[wave][r][ 0 + t] = acc0[reg];
        accL[wave][r][16 + t] = acc1[reg];
        accL[wave][r][32 + t] = acc2[reg];
        accL[wave][r][48 + t] = acc3[reg];
    }
    if (t == 0){
#pragma unroll
        for (int reg = 0; reg < 4; reg++) Sl[wave][q*4 + reg] = sacc[reg];  // row-sum, all cols equal
    }
    __syncthreads();
    // combine: 256 threads x 4 floats = 16 rows x 64 d  (R5-validated)
    const int tid = threadIdx.x;
    const int row = tid >> 4;
    const int d   = (tid & 15) * 4;
    f32x4 v0 = *reinterpret_cast<const f32x4*>(&accL[0][row][d]);
    f32x4 v1 = *reinterpret_cast<const f32x4*>(&accL[1][row][d]);
    f32x4 v2 = *reinterpret_cast<const f32x4*>(&accL[2][row][d]);
    f32x4 v3 = *reinterpret_cast<const f32x4*>(&accL[3][row][d]);
    float Ssum = Sl[0][row] + Sl[1][row] + Sl[2][row] + Sl[3][row];
    float rS = 1.0f / Ssum;
    f32x4 v;
#pragma unroll
    for (int c = 0; c < 4; c++){
        float vv = (v0[c] + v1[c] + v2[c] + v3[c]) * rS;
        v[c] = vv > 0.f ? vv : (__expf(vv) - 1.0f);   // ELU
    }
    *reinterpret_cast<f32x4*>(out + (b*2048 + i0 + row)*256 + head*64 + d) = v;
}

extern "C" void kernel_launch(void* const* d_in, const int* in_sizes, int n_in,
                              void* d_out, int out_size, void* d_ws, size_t ws_size,
                              hipStream_t stream) {
    const float* x     = (const float*)d_in[0];  // [4,2048,256] f32
    const int*   Amask = (const int*)d_in[1];    // [2048,2048] int32
    const float* W     = (const float*)d_in[2];  // [256,256] f32
    const float* a_src = (const float*)d_in[3];  // [4,64] f32
    const float* a_dst = (const float*)d_in[4];  // [4,64] f32
    float* out = (float*)d_out;                  // [4,2048,256] f32

    char* ws = (char*)d_ws;
    unsigned short*     hTt  = (unsigned short*)(ws);                    // 4 MB
    unsigned long long* bits = (unsigned long long*)(ws + (4u<<20));     // 512 KB
    unsigned short*     WT   = (unsigned short*)(ws + (4u<<20) + (512u<<10)); // 128 KB
    float*              src  = (float*)(ws + (4u<<20) + (640u<<10));     // 128 KB
    float*              dst  = (float*)(ws + (4u<<20) + (768u<<10));     // 128 KB

    hipLaunchKernelGGL(k_wt,   dim3(256),      dim3(256), 0, stream, W, WT);
    hipLaunchKernelGGL(k_bits, dim3(2048),     dim3(256), 0, stream, Amask, bits);
    hipLaunchKernelGGL(k_gemm, dim3(128),      dim3(256), 0, stream, x, WT, a_src, a_dst, hTt, src, dst);
    hipLaunchKernelGGL(k_attn, dim3(16, 128),  dim3(256), 0, stream, hTt, (const unsigned int*)bits, src, dst, out);
}

// Round 7
// 123.035 us; speedup vs baseline: 1.1636x; 1.1636x over previous
//
#include <hip/hip_runtime.h>

typedef float  f32x4 __attribute__((ext_vector_type(4)));
typedef short  s16x8 __attribute__((ext_vector_type(8)));

__device__ __forceinline__ unsigned short f2bf(float f){
    unsigned int u = __float_as_uint(f);
    u = u + 0x7FFFu + ((u >> 16) & 1u);      // RNE
    return (unsigned short)(u >> 16);
}

// ---------------- K0a: transpose+cast W[256][256] f32 -> WT bf16 [c][k] ----------------
__global__ void k_wt(const float* __restrict__ W, unsigned short* __restrict__ WT){
    int c = blockIdx.x, k = threadIdx.x;
    WT[c*256 + k] = f2bf(W[k*256 + c]);
}

// ---------------- K0b: mask -> bitmask (1 bit per entry), row-major u64 chunks ----------
__global__ void k_bits(const int* __restrict__ mask, unsigned long long* __restrict__ bits64){
    int i = blockIdx.x;
    int wave = threadIdx.x >> 6, lane = threadIdx.x & 63;
    for (int c = wave; c < 32; c += 4){
        int v = mask[i*2048 + c*64 + lane];
        unsigned long long b = __ballot(v != 0);
        if (lane == 0) bits64[i*32 + c] = b;
    }
}

// ---------------- K1: h = x @ W, fused src/dst — R5 version verbatim (grid 128x4) --------
__global__ __launch_bounds__(256) void k_gemm(const float* __restrict__ x,
        const unsigned short* __restrict__ WT,
        const float* __restrict__ a_src, const float* __restrict__ a_dst,
        unsigned short* __restrict__ hTt, float* __restrict__ src, float* __restrict__ dst){
    const int wave = threadIdx.x >> 6, lane = threadIdx.x & 63;
    const int q = lane >> 4, t = lane & 15;
    const int m0 = blockIdx.x*64 + wave*16;   // row tile (r = b*2048+n)
    const int head = blockIdx.y;
    f32x4 acc[4] = {{0,0,0,0},{0,0,0,0},{0,0,0,0},{0,0,0,0}};
    const int row = m0 + t;
    for (int k = 0; k < 256; k += 32){
        int kk = k + q*8;
        const float* xp = x + row*256 + kk;
        f32x4 x0 = *reinterpret_cast<const f32x4*>(xp);
        f32x4 x1 = *reinterpret_cast<const f32x4*>(xp + 4);
        s16x8 a;
#pragma unroll
        for (int j = 0; j < 4; j++){ a[j] = (short)f2bf(x0[j]); a[j+4] = (short)f2bf(x1[j]); }
#pragma unroll
        for (int dblk = 0; dblk < 4; dblk++){
            s16x8 bfr = *reinterpret_cast<const s16x8*>(WT + (head*64 + dblk*16 + t)*256 + kk);
            acc[dblk] = __builtin_amdgcn_mfma_f32_16x16x32_bf16(a, bfr, acc[dblk], 0, 0, 0);
        }
    }
    const int b = m0 >> 11;                   // tile never straddles batch boundary
    const int bh = b*4 + head;
    const int jb = (m0 & 2047) >> 4;
    float as_[4], ad_[4];
#pragma unroll
    for (int dblk = 0; dblk < 4; dblk++){
        as_[dblk] = a_src[head*64 + dblk*16 + t];
        ad_[dblk] = a_dst[head*64 + dblk*16 + t];
    }
#pragma unroll
    for (int reg = 0; reg < 4; reg++){
        float sv = acc[0][reg]*as_[0] + acc[1][reg]*as_[1] + acc[2][reg]*as_[2] + acc[3][reg]*as_[3];
        float dv = acc[0][reg]*ad_[0] + acc[1][reg]*ad_[1] + acc[2][reg]*ad_[2] + acc[3][reg]*ad_[3];
#pragma unroll
        for (int off = 1; off < 16; off <<= 1){
            sv += __shfl_xor(sv, off);
            dv += __shfl_xor(dv, off);
        }
        if (t == 0){
            int n = (m0 & 2047) + q*4 + reg;
            src[bh*2048 + n] = sv;
            dst[bh*2048 + n] = dv;
        }
    }
#pragma unroll
    for (int dblk = 0; dblk < 4; dblk++){
        int d = dblk*16 + t;
#pragma unroll
        for (int reg = 0; reg < 4; reg++){
            int jj = q*4 + reg;               // n = m0 + jj
            hTt[((bh*128 + jb)*64 + d)*16 + jj] = f2bf(acc[dblk][reg]);
        }
    }
}

// ---------------- K2: fused masked softmax + PV + ELU ----------------
// grid (16 bh, 64 i-tiles of 32 rows), block 256 = 4 waves, wave = 512-wide j-chunk,
// 2 A-fragments (32 i-rows) per wave; ones-MFMA row sums (R6-validated).
__device__ __forceinline__ s16x8 make_p(unsigned int bs, float vsrc, f32x4 d0, f32x4 d1, float NEGINF){
    float e[8];
#pragma unroll
    for (int jj = 0; jj < 8; jj++){
        float dvv = (jj < 4) ? d0[jj] : d1[jj-4];
        float lg = vsrc + dvv;
        lg = fmaxf(lg, 0.2f*lg);                       // leaky relu
        lg = ((bs >> jj) & 1u) ? lg : NEGINF;          // mask -> exp = 0
        e[jj] = __expf(lg);                            // bounded logits: no max-sub
    }
    union { unsigned int u[4]; s16x8 s; } pk;
#pragma unroll
    for (int p = 0; p < 4; p++)
        pk.u[p] = __builtin_amdgcn_perm(__float_as_uint(e[2*p+1]), __float_as_uint(e[2*p]), 0x07060302u);
    return pk.s;
}

__global__ __launch_bounds__(256, 4) void k_attn(const unsigned short* __restrict__ hTt,
        const unsigned int* __restrict__ bits, const float* __restrict__ src,
        const float* __restrict__ dst, float* __restrict__ out){
    __shared__ float accL[4][16][64];
    __shared__ float Sl[4][16];
    const int bh = blockIdx.x;
    const int b = bh >> 2, head = bh & 3;
    const int wave = threadIdx.x >> 6, lane = threadIdx.x & 63;
    const int q = lane >> 4, t = lane & 15, q8 = q*8;
    const int i0 = blockIdx.y*32;
    const float NEGINF = -__builtin_inff();
    const float vsrc0 = src[bh*2048 + i0 + t];
    const float vsrc1 = src[bh*2048 + i0 + 16 + t];
    const unsigned int* bR0 = bits + (i0 + t)*64 + wave*16;   // u32 word covers 32 j-cols
    const unsigned int* bR1 = bR0 + 16*64;
    const float* dR = dst + bh*2048 + wave*512 + q8;
    const unsigned short* vB = hTt + bh*131072 + wave*32768 + (q>>1)*1024 + (q&1)*8 + t*16;
    f32x4 a00={0,0,0,0},a01={0,0,0,0},a02={0,0,0,0},a03={0,0,0,0};
    f32x4 a10={0,0,0,0},a11={0,0,0,0},a12={0,0,0,0},a13={0,0,0,0};
    f32x4 s0acc={0,0,0,0}, s1acc={0,0,0,0};
    s16x8 ones;
#pragma unroll
    for (int j = 0; j < 8; j++) ones[j] = (short)0x3F80;   // bf16 1.0
    for (int it = 0; it < 16; ++it){
        const unsigned short* vp = vB + it*2048;
        s16x8 h0 = *reinterpret_cast<const s16x8*>(vp);
        s16x8 h1 = *reinterpret_cast<const s16x8*>(vp + 256);
        s16x8 h2 = *reinterpret_cast<const s16x8*>(vp + 512);
        s16x8 h3 = *reinterpret_cast<const s16x8*>(vp + 768);
        unsigned int bs0 = bR0[it] >> q8;
        unsigned int bs1 = bR1[it] >> q8;
        f32x4 d0 = *reinterpret_cast<const f32x4*>(dR + it*32);
        f32x4 d1 = *reinterpret_cast<const f32x4*>(dR + it*32 + 4);
        s16x8 p0 = make_p(bs0, vsrc0, d0, d1, NEGINF);
        s16x8 p1 = make_p(bs1, vsrc1, d0, d1, NEGINF);
        a00 = __builtin_amdgcn_mfma_f32_16x16x32_bf16(p0, h0, a00, 0,0,0);
        a01 = __builtin_amdgcn_mfma_f32_16x16x32_bf16(p0, h1, a01, 0,0,0);
        a02 = __builtin_amdgcn_mfma_f32_16x16x32_bf16(p0, h2, a02, 0,0,0);
        a03 = __builtin_amdgcn_mfma_f32_16x16x32_bf16(p0, h3, a03, 0,0,0);
        s0acc = __builtin_amdgcn_mfma_f32_16x16x32_bf16(p0, ones, s0acc, 0,0,0);
        a10 = __builtin_amdgcn_mfma_f32_16x16x32_bf16(p1, h0, a10, 0,0,0);
        a11 = __builtin_amdgcn_mfma_f32_16x16x32_bf16(p1, h1, a11, 0,0,0);
        a12 = __builtin_amdgcn_mfma_f32_16x16x32_bf16(p1, h2, a12, 0,0,0);
        a13 = __builtin_amdgcn_mfma_f32_16x16x32_bf16(p1, h3, a13, 0,0,0);
        s1acc = __builtin_amdgcn_mfma_f32_16x16x32_bf16(p1, ones, s1acc, 0,0,0);
    }
    // ---- epilogue: R5/R6-validated 16-row combine, executed twice ----
#pragma unroll
    for (int half = 0; half < 2; half++){
        f32x4 c0 = half ? a10 : a00;
        f32x4 c1 = half ? a11 : a01;
        f32x4 c2 = half ? a12 : a02;
        f32x4 c3 = half ? a13 : a03;
        f32x4 sc = half ? s1acc : s0acc;
        if (half) __syncthreads();            // previous combine reads done before overwrite
#pragma unroll
        for (int reg = 0; reg < 4; reg++){
            int r = q*4 + reg;
            accL[wave][r][ 0 + t] = c0[reg];
            accL[wave][r][16 + t] = c1[reg];
            accL[wave][r][32 + t] = c2[reg];
            accL[wave][r][48 + t] = c3[reg];
        }
        if (t == 0){
#pragma unroll
            for (int reg = 0; reg < 4; reg++) Sl[wave][q*4 + reg] = sc[reg];  // all cols equal
        }
        __syncthreads();
        const int tid = threadIdx.x;
        const int row = tid >> 4;
        const int d   = (tid & 15) * 4;
        f32x4 v0 = *reinterpret_cast<const f32x4*>(&accL[0][row][d]);
        f32x4 v1 = *reinterpret_cast<const f32x4*>(&accL[1][row][d]);
        f32x4 v2 = *reinterpret_cast<const f32x4*>(&accL[2][row][d]);
        f32x4 v3 = *reinterpret_cast<const f32x4*>(&accL[3][row][d]);
        float Ssum = Sl[0][row] + Sl[1][row] + Sl[2][row] + Sl[3][row];
        float rS = 1.0f / Ssum;
        f32x4 v;
#pragma unroll
        for (int c = 0; c < 4; c++){
            float vv = (v0[c] + v1[c] + v2[c] + v3[c]) * rS;
            v[c] = vv > 0.f ? vv : (__expf(vv) - 1.0f);   // ELU
        }
        *reinterpret_cast<f32x4*>(out + (b*2048 + i0 + half*16 + row)*256 + head*64 + d) = v;
    }
}

extern "C" void kernel_launch(void* const* d_in, const int* in_sizes, int n_in,
                              void* d_out, int out_size, void* d_ws, size_t ws_size,
                              hipStream_t stream) {
    const float* x     = (const float*)d_in[0];  // [4,2048,256] f32
    const int*   Amask = (const int*)d_in[1];    // [2048,2048] int32
    const float* W     = (const float*)d_in[2];  // [256,256] f32
    const float* a_src = (const float*)d_in[3];  // [4,64] f32
    const float* a_dst = (const float*)d_in[4];  // [4,64] f32
    float* out = (float*)d_out;                  // [4,2048,256] f32

    char* ws = (char*)d_ws;
    unsigned short*     hTt  = (unsigned short*)(ws);                    // 4 MB
    unsigned long long* bits = (unsigned long long*)(ws + (4u<<20));     // 512 KB
    unsigned short*     WT   = (unsigned short*)(ws + (4u<<20) + (512u<<10)); // 128 KB
    float*              src  = (float*)(ws + (4u<<20) + (640u<<10));     // 128 KB
    float*              dst  = (float*)(ws + (4u<<20) + (768u<<10));     // 128 KB

    hipLaunchKernelGGL(k_wt,   dim3(256),     dim3(256), 0, stream, W, WT);
    hipLaunchKernelGGL(k_bits, dim3(2048),    dim3(256), 0, stream, Amask, bits);
    hipLaunchKernelGGL(k_gemm, dim3(128, 4),  dim3(256), 0, stream, x, WT, a_src, a_dst, hTt, src, dst);
    hipLaunchKernelGGL(k_attn, dim3(16, 64),  dim3(256), 0, stream, hTt, (const unsigned int*)bits, src, dst, out);
}